// Round 1
// baseline (3530.374 us; speedup 1.0000x reference)
//
#include <hip/hip_runtime.h>
#include <hip/hip_fp16.h>

#define TB 8      // batch
#define TD 256    // d_model
#define TE 2048   // edges (sequence)
#define TH 8      // heads

typedef _Float16 h2_t __attribute__((ext_vector_type(2)));

static __device__ __forceinline__ float fdot2f(h2_t a, h2_t b, float c){
#if __has_builtin(__builtin_amdgcn_fdot2)
  return __builtin_amdgcn_fdot2(a, b, c, false);
#else
  return c + (float)a[0]*(float)b[0] + (float)a[1]*(float)b[1];
#endif
}
static __device__ __forceinline__ unsigned int packh2(float a, float b){
  __half2 h = __floats2half2_rn(a, b);
  return __builtin_bit_cast(unsigned int, h);
}
static __device__ __forceinline__ h2_t u2h(unsigned int u){
  return __builtin_bit_cast(h2_t, u);
}

// ---------------- mask dtype detection: 1 = int32, 0 = bytes ----------------
__global__ void k_detect(const unsigned int* __restrict__ mraw, unsigned int* __restrict__ flag){
  __shared__ int oks;
  if(threadIdx.x == 0) oks = 1;
  __syncthreads();
  int ok = 1;
  for(int i = threadIdx.x; i < 4096; i += 256){
    if(mraw[i] > 1u) ok = 0;
  }
  if(!ok) atomicAnd(&oks, 0);
  __syncthreads();
  if(threadIdx.x == 0) *flag = (unsigned int)oks;
}

// ---------------- pack mask rows into bitmask [B*E][64 words] ----------------
__global__ __launch_bounds__(256) void k_pack(const unsigned int* __restrict__ mraw,
                       const unsigned int* __restrict__ flag,
                       unsigned int* __restrict__ packed){
  const int t = threadIdx.x;
  const int row = blockIdx.x*4 + (t >> 6);
  const int w = t & 63;
  const size_t base = (size_t)row*TE + (size_t)w*32;
  unsigned int bits = 0;
  if(*flag){
    const unsigned int* p = mraw + base;
    #pragma unroll
    for(int j=0;j<32;j++) bits |= (p[j] & 1u) << j;
  } else {
    const unsigned char* p = (const unsigned char*)mraw + base;
    #pragma unroll
    for(int j=0;j<32;j++) bits |= (unsigned int)(p[j] != 0) << j;
  }
  packed[(size_t)row*64 + w] = bits;
}

// ---------------- denom[b][k] = sum_q mask[b][q][k] ----------------
__global__ __launch_bounds__(256) void k_denom(const unsigned int* __restrict__ mraw,
                        const unsigned int* __restrict__ flag,
                        float* __restrict__ denom){
  const int b = blockIdx.z;
  const int k = blockIdx.x*256 + threadIdx.x;
  const int q0 = blockIdx.y*64;
  float cnt = 0.f;
  if(*flag){
    const unsigned int* p = mraw + ((size_t)b*TE + q0)*TE + k;
    for(int q=0;q<64;q++) cnt += (float)(p[(size_t)q*TE] & 1u);
  } else {
    const unsigned char* p = (const unsigned char*)mraw + ((size_t)b*TE + q0)*TE + k;
    for(int q=0;q<64;q++) cnt += (float)(p[(size_t)q*TE] != 0);
  }
  atomicAdd(&denom[b*TE + k], cnt);
}

// ---------------- transpose + LayerNorm + Q/K/V projections ----------------
// grid (E/16, B), 256 threads. Tile: 16 edges x 256 dims.
__global__ __launch_bounds__(256) void k_qkv(
    const float* __restrict__ x, const float* __restrict__ wqs, const float* __restrict__ wks,
    const float* __restrict__ wvs, const float* __restrict__ gamma, const float* __restrict__ beta,
    float* __restrict__ qw, float* __restrict__ kw, float* __restrict__ vw){
  __shared__ float xs[16][260];
  __shared__ float qi[16][260];
  __shared__ float mu_s[16], rs_s[16];
  const int t = threadIdx.x;
  const int b = blockIdx.y;
  const int e0 = blockIdx.x*16;

  for(int i=t;i<16*256;i+=256){
    int el = i & 15, dd = i >> 4;
    xs[el][dd] = x[((size_t)(b*TD + dd))*TE + e0 + el];
  }
  __syncthreads();
  {
    int row = t >> 4, j = t & 15;
    float s1=0.f, s2=0.f;
    #pragma unroll
    for(int i=0;i<16;i++){ float v = xs[row][j*16+i]; s1 += v; s2 += v*v; }
    #pragma unroll
    for(int off=1; off<16; off<<=1){ s1 += __shfl_xor(s1, off); s2 += __shfl_xor(s2, off); }
    if(j==0){
      float m = s1 * (1.f/256.f);
      float var = s2 * (1.f/256.f) - m*m;
      mu_s[row] = m;
      rs_s[row] = rsqrtf(var + 1e-6f);
    }
  }
  __syncthreads();
  for(int i=t;i<16*256;i+=256){
    int r = i >> 8, dd = i & 255;
    qi[r][dd] = (xs[r][dd] - mu_s[r]) * rs_s[r] * gamma[dd] + beta[dd];
  }
  __syncthreads();

  const int c = t;
  float aq[16], ak[16], av[16];
  #pragma unroll
  for(int r=0;r<16;r++){ aq[r]=0.f; ak[r]=0.f; av[r]=0.f; }
  for(int dd=0; dd<256; dd+=4){
    float wq0 = wqs[(dd+0)*256 + c], wq1 = wqs[(dd+1)*256 + c];
    float wq2 = wqs[(dd+2)*256 + c], wq3 = wqs[(dd+3)*256 + c];
    float wk0 = wks[(dd+0)*256 + c], wk1 = wks[(dd+1)*256 + c];
    float wk2 = wks[(dd+2)*256 + c], wk3 = wks[(dd+3)*256 + c];
    float wv0 = wvs[(dd+0)*256 + c], wv1 = wvs[(dd+1)*256 + c];
    float wv2 = wvs[(dd+2)*256 + c], wv3 = wvs[(dd+3)*256 + c];
    #pragma unroll
    for(int r=0;r<16;r++){
      float4 a  = *(const float4*)&qi[r][dd];
      float4 s4 = *(const float4*)&xs[r][dd];
      aq[r] += a.x*wq0  + a.y*wq1  + a.z*wq2  + a.w*wq3;
      ak[r] += s4.x*wk0 + s4.y*wk1 + s4.z*wk2 + s4.w*wk3;
      av[r] += s4.x*wv0 + s4.y*wv1 + s4.z*wv2 + s4.w*wv3;
    }
  }
  const int hh = c >> 5, d2 = c & 31;
  const float scl = 0.17677669529663687f;   // 1/sqrt(DK)
  const size_t hb = ((size_t)(b*TH + hh))*TE;
  #pragma unroll
  for(int r=0;r<16;r++){
    size_t idx = (hb + e0 + r)*32 + d2;
    qw[idx] = aq[r]*scl;
    kw[idx] = ak[r];
    vw[idx] = av[r];
  }
}

// ---------------- attention: scores+mask -> softmax -> attn write + PV + per-edge num ----------------
// grid = B*H*E/8 = 16384 blocks, 256 threads (4 waves, 2 q-rows/wave).
__global__ __launch_bounds__(256) void k_attn(
    const float* __restrict__ qw, const float* __restrict__ kw, const float* __restrict__ vw,
    const unsigned int* __restrict__ packed,
    float* __restrict__ attn, float* __restrict__ ow, float* __restrict__ num){
  __shared__ float q_f[8][32];
  __shared__ unsigned int mb[8][64];
  __shared__ unsigned int tile[2][1024];                 // K (fp16 pairs, swizzled) / V (fp16 pairs)
  __shared__ __align__(16) unsigned short sc[8][2056];   // raw scores -> exp(s-m), fp16
  __shared__ float rl_s[8];

  const int t = threadIdx.x;
  const int bid = blockIdx.x;
  const int q0 = (bid & 255) * 8;
  const int h  = (bid >> 8) & 7;
  const int b  = bid >> 11;
  const size_t bh = (size_t)(b*TH + h) * TE;
  const float* Kg = kw + bh*32;
  const float* Vg = vw + bh*32;

  { int r = t >> 5, d = t & 31;
    q_f[r][d] = qw[(bh + q0 + r)*32 + d]; }
  for(int i=t;i<512;i+=256){
    int r = i >> 6, w = i & 63;
    mb[r][w] = packed[((size_t)b*TE + q0 + r)*64 + w];
  }
  __syncthreads();

  const int ln = t & 63;
  const int wv = t >> 6;
  h2_t qa[16], qb[16];
  #pragma unroll
  for(int j=0;j<16;j++){
    qa[j][0] = (_Float16)q_f[2*wv][2*j];   qa[j][1] = (_Float16)q_f[2*wv][2*j+1];
    qb[j][0] = (_Float16)q_f[2*wv+1][2*j]; qb[j][1] = (_Float16)q_f[2*wv+1][2*j+1];
  }

#define STAGE_K(BUF, KT) \
  for(int i=t;i<1024;i+=256){ \
    int row = i >> 4, j = i & 15; \
    float2 kv = *(const float2*)(Kg + ((size_t)((KT) + row))*32 + 2*j); \
    tile[BUF][(row<<4) | (j ^ (((row>>1)&3)<<2))] = packh2(kv.x, kv.y); \
  }
#define STAGE_V(BUF, KT) \
  for(int i=t;i<1024;i+=256){ \
    int pr = i >> 5, dd = i & 31; \
    const float* sv = Vg + ((size_t)((KT) + 2*pr))*32 + dd; \
    tile[BUF][i] = packh2(sv[0], sv[32]); \
  }

  // ---- phase 1: scores (fp16 dot) -> sc ----
  STAGE_K(0, 0)
  for(int it=0; it<32; ++it){
    __syncthreads();
    if(it+1 < 32){ STAGE_K((it+1)&1, (it+1)*64) }
    const unsigned int* kro = &tile[it & 1][ln << 4];
    const int sw = ((ln >> 1) & 3) << 2;
    uint4 kq0 = *(const uint4*)&kro[0 ^ sw];
    uint4 kq1 = *(const uint4*)&kro[4 ^ sw];
    uint4 kq2 = *(const uint4*)&kro[8 ^ sw];
    uint4 kq3 = *(const uint4*)&kro[12 ^ sw];
    h2_t kh[16];
    kh[0]=u2h(kq0.x); kh[1]=u2h(kq0.y); kh[2]=u2h(kq0.z); kh[3]=u2h(kq0.w);
    kh[4]=u2h(kq1.x); kh[5]=u2h(kq1.y); kh[6]=u2h(kq1.z); kh[7]=u2h(kq1.w);
    kh[8]=u2h(kq2.x); kh[9]=u2h(kq2.y); kh[10]=u2h(kq2.z); kh[11]=u2h(kq2.w);
    kh[12]=u2h(kq3.x); kh[13]=u2h(kq3.y); kh[14]=u2h(kq3.z); kh[15]=u2h(kq3.w);
    float s0 = 0.f, s1 = 0.f;
    #pragma unroll
    for(int j=0;j<16;j++){ s0 = fdot2f(qa[j], kh[j], s0); s1 = fdot2f(qb[j], kh[j], s1); }
    const int kk = it*64 + ln;
    const int wi = kk >> 5, bi = kk & 31;
    s0 = ((mb[2*wv][wi]   >> bi) & 1u) ? s0 : -1e9f;
    s1 = ((mb[2*wv+1][wi] >> bi) & 1u) ? s1 : -1e9f;
    sc[2*wv][kk]   = __half_as_ushort(__float2half(s0));
    sc[2*wv+1][kk] = __half_as_ushort(__float2half(s1));
  }
  __syncthreads();

  // ---- phase 2: row max, e = exp(s-m) stored back, rl = 1/sum ----
  {
    int row = t >> 5, j = t & 31;
    float m = -1e30f;
    for(int i=0;i<64;i++){
      float s = __half2float(__ushort_as_half(sc[row][j + 32*i]));
      m = fmaxf(m, s);
    }
    #pragma unroll
    for(int off=1; off<32; off<<=1) m = fmaxf(m, __shfl_xor(m, off));
    float lsum = 0.f;
    for(int i=0;i<64;i++){
      int k = j + 32*i;
      float s = __half2float(__ushort_as_half(sc[row][k]));
      float e = __expf(s - m);
      sc[row][k] = __half_as_ushort(__float2half(e));
      lsum += e;
    }
    #pragma unroll
    for(int off=1; off<32; off<<=1) lsum += __shfl_xor(lsum, off);
    if(j == 0) rl_s[row] = 1.f / lsum;
  }
  __syncthreads();

  // ---- phase 3: write attn = e*rl, accumulate per-edge numerator ----
  float pacc[8];
  #pragma unroll
  for(int i=0;i<8;i++) pacc[i]=0.f;
  float* attn_base = attn + (bh + q0)*TE;
  for(int r2=0;r2<8;r2++){
    float rl = rl_s[r2];
    #pragma unroll
    for(int m2=0;m2<8;m2++){
      int k = t + (m2<<8);
      float e = __half2float(__ushort_as_half(sc[r2][k]));
      float p = e * rl;
      attn_base[(size_t)r2*TE + k] = p;
      pacc[m2] += p;
    }
  }
  #pragma unroll
  for(int m2=0;m2<8;m2++) atomicAdd(&num[(size_t)b*TE + t + (m2<<8)], pacc[m2]);
  __syncthreads();

  // ---- phase 4: PV (fp16 dot on e pairs, scale by rl at end) ----
  float acc[8];
  #pragma unroll
  for(int i=0;i<8;i++) acc[i]=0.f;
  const int d2 = t & 31, rep = t >> 5;
  STAGE_V(0, 0)
  for(int it=0; it<32; ++it){
    __syncthreads();
    if(it+1 < 32){ STAGE_V((it+1)&1, (it+1)*64) }
    const unsigned int* vt = tile[it & 1];
    const int gp0 = it*32;
    #pragma unroll
    for(int pp=0; pp<4; pp++){
      int pair = pp*8 + rep;
      h2_t v2 = u2h(vt[pair*32 + d2]);
      int gp = gp0 + pair;
      #pragma unroll
      for(int r=0;r<8;r++){
        h2_t e2 = u2h(*(const unsigned int*)&sc[r][2*gp]);
        acc[r] = fdot2f(e2, v2, acc[r]);
      }
    }
  }
  __syncthreads();
  // reduce partials across 8 rep groups via scratch overlaid on sc
  float* scratch = (float*)sc;
  #pragma unroll
  for(int r=0;r<8;r++) scratch[r*288 + d2*9 + rep] = acc[r];
  __syncthreads();
  {
    int r = t >> 5, dd = t & 31;
    float o = 0.f;
    #pragma unroll
    for(int rp=0; rp<8; rp++) o += scratch[r*288 + dd*9 + rp];
    o *= rl_s[r];
    ow[((size_t)b*TE + q0 + r)*256 + h*32 + dd] = o;
  }
#undef STAGE_K
#undef STAGE_V
}

// ---------------- output projection + residual + transpose ----------------
__global__ __launch_bounds__(256) void k_fc(
    const float* __restrict__ ow, const float* __restrict__ wfc, const float* __restrict__ x,
    float* __restrict__ xout){
  __shared__ float os[16][260];
  __shared__ float xt[16][260];
  const int t = threadIdx.x;
  const int b = blockIdx.y;
  const int e0 = blockIdx.x * 16;
  for(int i=t;i<4096;i+=256){
    int r = i >> 8, dd = i & 255;
    os[r][dd] = ow[((size_t)b*TE + e0 + r)*256 + dd];
  }
  for(int i=t;i<4096;i+=256){
    int el = i & 15, dd = i >> 4;
    xt[el][dd] = x[((size_t)(b*TD + dd))*TE + e0 + el];
  }
  __syncthreads();
  const int c = t;
  float f[16];
  #pragma unroll
  for(int r=0;r<16;r++) f[r] = 0.f;
  for(int dd=0; dd<256; dd+=4){
    float w0 = wfc[(dd+0)*256 + c], w1 = wfc[(dd+1)*256 + c];
    float w2 = wfc[(dd+2)*256 + c], w3 = wfc[(dd+3)*256 + c];
    #pragma unroll
    for(int r=0;r<16;r++){
      float4 o4 = *(const float4*)&os[r][dd];
      f[r] += o4.x*w0 + o4.y*w1 + o4.z*w2 + o4.w*w3;
    }
  }
  __syncthreads();
  #pragma unroll
  for(int r=0;r<16;r++) os[r][c] = f[r] + xt[r][c];
  __syncthreads();
  for(int i=t;i<4096;i+=256){
    int el = i & 15, dd = i >> 4;
    xout[((size_t)(b*TD + dd))*TE + e0 + el] = os[el][dd];
  }
}

// ---------------- per-edge final: num / (H * denom) ----------------
__global__ void k_edge(const float* __restrict__ num, const float* __restrict__ denom,
                       float* __restrict__ pe){
  int idx = blockIdx.x*256 + threadIdx.x;
  pe[idx] = num[idx] / (8.f * denom[idx]);
}

extern "C" void kernel_launch(void* const* d_in, const int* in_sizes, int n_in,
                              void* d_out, int out_size, void* d_ws, size_t ws_size,
                              hipStream_t stream){
  const float* x   = (const float*)d_in[0];
  const unsigned int* mraw = (const unsigned int*)d_in[1];
  const float* wqs = (const float*)d_in[2];
  const float* wks = (const float*)d_in[3];
  const float* wvs = (const float*)d_in[4];
  const float* wfc = (const float*)d_in[5];
  const float* gamma = (const float*)d_in[6];
  const float* beta  = (const float*)d_in[7];

  float* xout = (float*)d_out;                               // [B,D,E]
  float* attn = xout + (size_t)TB*TD*TE;                     // [B,H,E,E]
  float* pe   = attn + (size_t)TB*TH*TE*TE;                  // [B,E]

  const size_t SZ = (size_t)TB*TH*TE*32;                     // 4,194,304 floats
  unsigned int* flag = (unsigned int*)d_ws;
  float* qw = (float*)((char*)d_ws + 256);
  float* kw = qw + SZ;
  float* vw = kw + SZ;
  float* ow = vw + SZ;                                       // [B,E,256] same size
  unsigned int* packed = (unsigned int*)(ow + SZ);           // 4 MB
  float* num   = (float*)(packed + (size_t)TB*TE*64);
  float* denom = num + (size_t)TB*TE;

  hipMemsetAsync(num, 0, (size_t)TB*TE*2*sizeof(float), stream);
  k_detect<<<1, 256, 0, stream>>>(mraw, flag);
  k_pack<<<TB*TE/4, 256, 0, stream>>>(mraw, flag, packed);
  k_denom<<<dim3(TE/256, 32, TB), 256, 0, stream>>>(mraw, flag, denom);
  k_qkv<<<dim3(TE/16, TB), 256, 0, stream>>>(x, wqs, wks, wvs, gamma, beta, qw, kw, vw);
  k_attn<<<TB*TH*TE/8, 256, 0, stream>>>(qw, kw, vw, packed, attn, ow, num);
  k_fc<<<dim3(TE/16, TB), 256, 0, stream>>>(ow, wfc, x, xout);
  k_edge<<<TB*TE/256, 256, 0, stream>>>(num, denom, pe);
}

// Round 2
// 687.867 us; speedup vs baseline: 5.1323x; 5.1323x over previous
//
#include <hip/hip_runtime.h>
#include <hip/hip_fp16.h>

#define TB 8      // batch
#define TD 256    // d_model
#define TE 2048   // edges (sequence)
#define TH 8      // heads

typedef _Float16 h8 __attribute__((ext_vector_type(8)));
typedef float    f4 __attribute__((ext_vector_type(4)));

static __device__ __forceinline__ unsigned int packh2(float a, float b){
  __half2 h = __floats2half2_rn(a, b);
  return __builtin_bit_cast(unsigned int, h);
}

// ---------------- mask dtype detection: 1 = int32, 0 = bytes ----------------
__global__ void k_detect(const unsigned int* __restrict__ mraw, unsigned int* __restrict__ flag){
  __shared__ int oks;
  if(threadIdx.x == 0) oks = 1;
  __syncthreads();
  int ok = 1;
  for(int i = threadIdx.x; i < 4096; i += 256){
    if(mraw[i] > 1u) ok = 0;
  }
  if(!ok) atomicAnd(&oks, 0);
  __syncthreads();
  if(threadIdx.x == 0) *flag = (unsigned int)oks;
}

// ---------------- pack mask rows into bitmask [B*E][64 words] ----------------
__global__ __launch_bounds__(256) void k_pack(const unsigned int* __restrict__ mraw,
                       const unsigned int* __restrict__ flag,
                       unsigned int* __restrict__ packed){
  const int t = threadIdx.x;
  const int row = blockIdx.x*4 + (t >> 6);
  const int w = t & 63;
  const size_t base = (size_t)row*TE + (size_t)w*32;
  unsigned int bits = 0;
  if(*flag){
    const unsigned int* p = mraw + base;
    #pragma unroll
    for(int j=0;j<32;j++) bits |= (p[j] & 1u) << j;
  } else {
    const unsigned char* p = (const unsigned char*)mraw + base;
    #pragma unroll
    for(int j=0;j<32;j++) bits |= (unsigned int)(p[j] != 0) << j;
  }
  packed[(size_t)row*64 + w] = bits;
}

// ---------------- denom[b][k] = sum_q mask[b][q][k] ----------------
__global__ __launch_bounds__(256) void k_denom(const unsigned int* __restrict__ mraw,
                        const unsigned int* __restrict__ flag,
                        float* __restrict__ denom){
  const int b = blockIdx.z;
  const int k = blockIdx.x*256 + threadIdx.x;
  const int q0 = blockIdx.y*64;
  float cnt = 0.f;
  if(*flag){
    const unsigned int* p = mraw + ((size_t)b*TE + q0)*TE + k;
    for(int q=0;q<64;q++) cnt += (float)(p[(size_t)q*TE] & 1u);
  } else {
    const unsigned char* p = (const unsigned char*)mraw + ((size_t)b*TE + q0)*TE + k;
    for(int q=0;q<64;q++) cnt += (float)(p[(size_t)q*TE] != 0);
  }
  atomicAdd(&denom[b*TE + k], cnt);
}

// ---------------- transpose + LayerNorm + Q/K/V projections (fp16 out) ----------------
// grid (E/16, B), 256 threads. Tile: 16 edges x 256 dims.
__global__ __launch_bounds__(256) void k_qkv(
    const float* __restrict__ x, const float* __restrict__ wqs, const float* __restrict__ wks,
    const float* __restrict__ wvs, const float* __restrict__ gamma, const float* __restrict__ beta,
    _Float16* __restrict__ qh, _Float16* __restrict__ kh, _Float16* __restrict__ vt){
  __shared__ float xs[16][260];
  __shared__ float qi[16][260];
  __shared__ float mu_s[16], rs_s[16];
  const int t = threadIdx.x;
  const int b = blockIdx.y;
  const int e0 = blockIdx.x*16;

  for(int i=t;i<16*256;i+=256){
    int el = i & 15, dd = i >> 4;
    xs[el][dd] = x[((size_t)(b*TD + dd))*TE + e0 + el];
  }
  __syncthreads();
  {
    int row = t >> 4, j = t & 15;
    float s1=0.f, s2=0.f;
    #pragma unroll
    for(int i=0;i<16;i++){ float v = xs[row][j*16+i]; s1 += v; s2 += v*v; }
    #pragma unroll
    for(int off=1; off<16; off<<=1){ s1 += __shfl_xor(s1, off); s2 += __shfl_xor(s2, off); }
    if(j==0){
      float m = s1 * (1.f/256.f);
      float var = s2 * (1.f/256.f) - m*m;
      mu_s[row] = m;
      rs_s[row] = rsqrtf(var + 1e-6f);
    }
  }
  __syncthreads();
  for(int i=t;i<16*256;i+=256){
    int r = i >> 8, dd = i & 255;
    qi[r][dd] = (xs[r][dd] - mu_s[r]) * rs_s[r] * gamma[dd] + beta[dd];
  }
  __syncthreads();

  const int c = t;
  float aq[16], ak[16], av[16];
  #pragma unroll
  for(int r=0;r<16;r++){ aq[r]=0.f; ak[r]=0.f; av[r]=0.f; }
  for(int dd=0; dd<256; dd+=4){
    float wq0 = wqs[(dd+0)*256 + c], wq1 = wqs[(dd+1)*256 + c];
    float wq2 = wqs[(dd+2)*256 + c], wq3 = wqs[(dd+3)*256 + c];
    float wk0 = wks[(dd+0)*256 + c], wk1 = wks[(dd+1)*256 + c];
    float wk2 = wks[(dd+2)*256 + c], wk3 = wks[(dd+3)*256 + c];
    float wv0 = wvs[(dd+0)*256 + c], wv1 = wvs[(dd+1)*256 + c];
    float wv2 = wvs[(dd+2)*256 + c], wv3 = wvs[(dd+3)*256 + c];
    #pragma unroll
    for(int r=0;r<16;r++){
      float4 a  = *(const float4*)&qi[r][dd];
      float4 s4 = *(const float4*)&xs[r][dd];
      aq[r] += a.x*wq0  + a.y*wq1  + a.z*wq2  + a.w*wq3;
      ak[r] += s4.x*wk0 + s4.y*wk1 + s4.z*wk2 + s4.w*wk3;
      av[r] += s4.x*wv0 + s4.y*wv1 + s4.z*wv2 + s4.w*wv3;
    }
  }
  const int hh = c >> 5, d2 = c & 31;
  const float scl = 0.17677669529663687f;   // 1/sqrt(DK)
  const size_t hb = ((size_t)(b*TH + hh))*TE;
  #pragma unroll
  for(int r=0;r<16;r++){
    size_t idx = (hb + e0 + r)*32 + d2;
    qh[idx] = (_Float16)(aq[r]*scl);
    kh[idx] = (_Float16)(ak[r]);
  }
  // V transposed: [bh][32][E]
  unsigned int pk[8];
  #pragma unroll
  for(int i2=0;i2<8;i2++) pk[i2] = packh2(av[2*i2], av[2*i2+1]);
  _Float16* vr = vt + ((size_t)(b*TH + hh)*32 + d2)*TE + e0;
  *(uint4*)&vr[0] = *(const uint4*)&pk[0];
  *(uint4*)&vr[8] = *(const uint4*)&pk[4];
}

// ---------------- MFMA attention ----------------
// 1 block = 64 q-rows of one (b,h). 4 waves x 16 rows. Two passes over K (recompute).
__device__ __forceinline__ void stage_k(_Float16 (*dst)[32], const _Float16* Kg, int kt, int t){
  int row = t >> 2, ch = t & 3;
  uint4 v = *(const uint4*)(Kg + ((size_t)(kt*64 + row))*32 + ch*8);
  *(uint4*)&dst[row][(ch ^ ((row>>1)&3))*8] = v;
}
__device__ __forceinline__ void stage_v(_Float16 (*dst)[64], const _Float16* Vg, int kt, int t){
  int d = t >> 3, ch = t & 7;
  uint4 v = *(const uint4*)(Vg + (size_t)d*TE + kt*64 + ch*8);
  *(uint4*)&dst[d][(ch ^ (d&7))*8] = v;
}

__global__ __launch_bounds__(256) void k_attn(
    const _Float16* __restrict__ qh, const _Float16* __restrict__ kh, const _Float16* __restrict__ vt,
    const unsigned int* __restrict__ packed,
    float* __restrict__ attn, float* __restrict__ ow, float* __restrict__ num){
  __shared__ __align__(16) _Float16 Kt[2][64][32];   // K tile, chunk-XOR swizzled
  __shared__ __align__(16) _Float16 Vt[2][32][64];   // V^T tile, chunk-XOR swizzled
  __shared__ __align__(16) _Float16 Pl[4][16][64];   // per-wave P tile (A-operand relayout)
  __shared__ unsigned int mb[64][66];                // mask bits for the 64 q-rows
  __shared__ float num_s[TE];

  const int t = threadIdx.x;
  int bid = blockIdx.x;
  bid = (bid & 7) * 256 + (bid >> 3);                // XCD-aware swizzle (2048 % 8 == 0)
  const int qt = bid & 31;
  const int bhid = bid >> 5;                         // 0..63
  const int h = bhid & 7, b = bhid >> 3;
  const size_t bh = (size_t)bhid * TE;
  const _Float16* Qg = qh + bh*32;
  const _Float16* Kg = kh + bh*32;
  const _Float16* Vg = vt + bh*32;                   // [32][TE]
  const int q0 = qt*64;

  const int wid = t >> 6, l = t & 63, g = l >> 4, c = l & 15;
  const f4 f4z = {0.f, 0.f, 0.f, 0.f};

  for(int i=t;i<TE;i+=256) num_s[i] = 0.f;
  for(int i=t;i<64*64;i+=256){
    int r = i >> 6, w = i & 63;
    mb[r][w] = packed[((size_t)b*TE + q0 + r)*64 + w];
  }

  // Q fragment (A-operand): lane holds row (l&15) of wave tile, k = g*8..g*8+7
  const h8 qf = *(const h8*)(Qg + (size_t)(q0 + wid*16 + c)*32 + g*8);

  float m[4], ll[4], rl[4];
  #pragma unroll
  for(int r=0;r<4;r++){ m[r] = -1e30f; ll[r] = 0.f; }

  // ---------------- pass 1: online row max + sum ----------------
  stage_k(Kt[0], Kg, 0, t);
  __syncthreads();
  for(int kt=0; kt<32; ++kt){
    const int bf = kt & 1;
    if(kt+1 < 32) stage_k(Kt[bf^1], Kg, kt+1, t);
    f4 s[4];
    #pragma unroll
    for(int j=0;j<4;j++){
      int row = j*16 + c;
      h8 kf = *(const h8*)&Kt[bf][row][(g ^ ((row>>1)&3))*8];
      s[j] = __builtin_amdgcn_mfma_f32_16x16x32_f16(qf, kf, f4z, 0, 0, 0);
    }
    #pragma unroll
    for(int r=0;r<4;r++){
      const unsigned int* mrow = mb[wid*16 + 4*g + r];
      float sv[4];
      #pragma unroll
      for(int j=0;j<4;j++){
        unsigned mw = mrow[kt*2 + (j>>1)];
        sv[j] = ((mw >> ((j&1)*16 + c)) & 1u) ? s[j][r] : -1e9f;
      }
      float tm = fmaxf(fmaxf(sv[0],sv[1]), fmaxf(sv[2],sv[3]));
      float mn = fmaxf(m[r], tm);
      float sum = __expf(sv[0]-mn) + __expf(sv[1]-mn) + __expf(sv[2]-mn) + __expf(sv[3]-mn);
      ll[r] = ll[r]*__expf(m[r]-mn) + sum;
      m[r] = mn;
    }
    __syncthreads();
  }

  // merge (m,l) across the 16 lanes holding the same row
  #pragma unroll
  for(int r=0;r<4;r++){
    #pragma unroll
    for(int off=1; off<16; off<<=1){
      float mo = __shfl_xor(m[r], off);
      float lo = __shfl_xor(ll[r], off);
      float mn = fmaxf(m[r], mo);
      ll[r] = ll[r]*__expf(m[r]-mn) + lo*__expf(mo-mn);
      m[r] = mn;
    }
    rl[r] = 1.f / ll[r];
  }

  // ---------------- pass 2: recompute, write attn, PV ----------------
  stage_k(Kt[0], Kg, 0, t);
  stage_v(Vt[0], Vg, 0, t);
  __syncthreads();
  f4 oacc[2] = {f4z, f4z};
  for(int kt=0; kt<32; ++kt){
    const int bf = kt & 1;
    if(kt+1 < 32){ stage_k(Kt[bf^1], Kg, kt+1, t); stage_v(Vt[bf^1], Vg, kt+1, t); }
    f4 s[4];
    #pragma unroll
    for(int j=0;j<4;j++){
      int row = j*16 + c;
      h8 kf = *(const h8*)&Kt[bf][row][(g ^ ((row>>1)&3))*8];
      s[j] = __builtin_amdgcn_mfma_f32_16x16x32_f16(qf, kf, f4z, 0, 0, 0);
    }
    float* ap = attn + ((size_t)(bh + q0 + wid*16 + 4*g))*TE + (size_t)kt*64 + c;
    #pragma unroll
    for(int j=0;j<4;j++){
      float cs = 0.f;
      #pragma unroll
      for(int r=0;r<4;r++){
        const int qrow = 4*g + r;
        unsigned mw = mb[wid*16 + qrow][kt*2 + (j>>1)];
        float sv = ((mw >> ((j&1)*16 + c)) & 1u) ? s[j][r] : -1e9f;
        float p = __expf(sv - m[r]) * rl[r];
        ap[(size_t)r*TE + j*16] = p;
        cs += p;
        Pl[wid][qrow][((((c + 16*j) >> 3) ^ (qrow & 7)) << 3) | (c & 7)] = (_Float16)p;
      }
      cs += __shfl_xor(cs, 16);
      cs += __shfl_xor(cs, 32);
      if(l < 16) atomicAdd(&num_s[kt*64 + j*16 + c], cs);
    }
    #pragma unroll
    for(int kc=0;kc<2;kc++){
      h8 pf = *(const h8*)&Pl[wid][c][(((kc*4+g) ^ (c & 7))) << 3];
      #pragma unroll
      for(int du=0;du<2;du++){
        int drow = du*16 + c;
        h8 vf = *(const h8*)&Vt[bf][drow][(((kc*4+g) ^ (drow & 7))) << 3];
        oacc[du] = __builtin_amdgcn_mfma_f32_16x16x32_f16(pf, vf, oacc[du], 0, 0, 0);
      }
    }
    __syncthreads();
  }

  // O write: [B,E,256] fp32
  #pragma unroll
  for(int du=0;du<2;du++){
    #pragma unroll
    for(int r=0;r<4;r++){
      ow[((size_t)b*TE + q0 + wid*16 + 4*g + r)*256 + h*32 + du*16 + c] = oacc[du][r];
    }
  }
  __syncthreads();
  for(int i=t;i<TE;i+=256) atomicAdd(&num[(size_t)b*TE + i], num_s[i]);
}

// ---------------- output projection + residual + transpose ----------------
__global__ __launch_bounds__(256) void k_fc(
    const float* __restrict__ ow, const float* __restrict__ wfc, const float* __restrict__ x,
    float* __restrict__ xout){
  __shared__ float os[16][260];
  __shared__ float xt[16][260];
  const int t = threadIdx.x;
  const int b = blockIdx.y;
  const int e0 = blockIdx.x * 16;
  for(int i=t;i<4096;i+=256){
    int r = i >> 8, dd = i & 255;
    os[r][dd] = ow[((size_t)b*TE + e0 + r)*256 + dd];
  }
  for(int i=t;i<4096;i+=256){
    int el = i & 15, dd = i >> 4;
    xt[el][dd] = x[((size_t)(b*TD + dd))*TE + e0 + el];
  }
  __syncthreads();
  const int c = t;
  float f[16];
  #pragma unroll
  for(int r=0;r<16;r++) f[r] = 0.f;
  for(int dd=0; dd<256; dd+=4){
    float w0 = wfc[(dd+0)*256 + c], w1 = wfc[(dd+1)*256 + c];
    float w2 = wfc[(dd+2)*256 + c], w3 = wfc[(dd+3)*256 + c];
    #pragma unroll
    for(int r=0;r<16;r++){
      float4 o4 = *(const float4*)&os[r][dd];
      f[r] += o4.x*w0 + o4.y*w1 + o4.z*w2 + o4.w*w3;
    }
  }
  __syncthreads();
  #pragma unroll
  for(int r=0;r<16;r++) os[r][c] = f[r] + xt[r][c];
  __syncthreads();
  for(int i=t;i<4096;i+=256){
    int el = i & 15, dd = i >> 4;
    xout[((size_t)(b*TD + dd))*TE + e0 + el] = os[el][dd];
  }
}

// ---------------- per-edge final: num / (H * denom) ----------------
__global__ void k_edge(const float* __restrict__ num, const float* __restrict__ denom,
                       float* __restrict__ pe){
  int idx = blockIdx.x*256 + threadIdx.x;
  pe[idx] = num[idx] / (8.f * denom[idx]);
}

extern "C" void kernel_launch(void* const* d_in, const int* in_sizes, int n_in,
                              void* d_out, int out_size, void* d_ws, size_t ws_size,
                              hipStream_t stream){
  const float* x   = (const float*)d_in[0];
  const unsigned int* mraw = (const unsigned int*)d_in[1];
  const float* wqs = (const float*)d_in[2];
  const float* wks = (const float*)d_in[3];
  const float* wvs = (const float*)d_in[4];
  const float* wfc = (const float*)d_in[5];
  const float* gamma = (const float*)d_in[6];
  const float* beta  = (const float*)d_in[7];

  float* xout = (float*)d_out;                               // [B,D,E]
  float* attn = xout + (size_t)TB*TD*TE;                     // [B,H,E,E]
  float* pe   = attn + (size_t)TB*TH*TE*TE;                  // [B,E]

  const size_t SZ = (size_t)TB*TH*TE*32;                     // 4,194,304
  unsigned int* flag = (unsigned int*)d_ws;
  _Float16* qhp = (_Float16*)((char*)d_ws + 256);
  _Float16* khp = qhp + SZ;
  _Float16* vtp = khp + SZ;                                  // V^T [B,H,32,E]
  float* ow = (float*)(vtp + SZ);                            // [B,E,256] fp32
  unsigned int* packed = (unsigned int*)(ow + SZ);           // 4 MB
  float* num   = (float*)(packed + (size_t)TB*TE*64);
  float* denom = num + (size_t)TB*TE;

  hipMemsetAsync(num, 0, (size_t)TB*TE*2*sizeof(float), stream);
  k_detect<<<1, 256, 0, stream>>>(mraw, flag);
  k_pack<<<TB*TE/4, 256, 0, stream>>>(mraw, flag, packed);
  k_denom<<<dim3(TE/256, 32, TB), 256, 0, stream>>>(mraw, flag, denom);
  k_qkv<<<dim3(TE/16, TB), 256, 0, stream>>>(x, wqs, wks, wvs, gamma, beta, qhp, khp, vtp);
  k_attn<<<TB*TH*TE/64, 256, 0, stream>>>(qhp, khp, vtp, packed, attn, ow, num);
  k_fc<<<dim3(TE/16, TB), 256, 0, stream>>>(ow, wfc, x, xout);
  k_edge<<<TB*TE/256, 256, 0, stream>>>(num, denom, pe);
}

// Round 3
// 579.972 us; speedup vs baseline: 6.0871x; 1.1860x over previous
//
#include <hip/hip_runtime.h>
#include <hip/hip_fp16.h>

#define TB 8      // batch
#define TD 256    // d_model
#define TE 2048   // edges (sequence)
#define TH 8      // heads

typedef _Float16 h8 __attribute__((ext_vector_type(8)));
typedef float    f4 __attribute__((ext_vector_type(4)));

static __device__ __forceinline__ unsigned int packh2(float a, float b){
  __half2 h = __floats2half2_rn(a, b);
  return __builtin_bit_cast(unsigned int, h);
}

// ---------------- mask dtype detection: 1 = int32, 0 = bytes ----------------
__global__ void k_detect(const unsigned int* __restrict__ mraw, unsigned int* __restrict__ flag){
  __shared__ int oks;
  if(threadIdx.x == 0) oks = 1;
  __syncthreads();
  int ok = 1;
  for(int i = threadIdx.x; i < 4096; i += 256){
    if(mraw[i] > 1u) ok = 0;
  }
  if(!ok) atomicAnd(&oks, 0);
  __syncthreads();
  if(threadIdx.x == 0) *flag = (unsigned int)oks;
}

// ---------------- pack mask rows into bitmask [B*E][64 words] ----------------
__global__ __launch_bounds__(256) void k_pack(const unsigned int* __restrict__ mraw,
                       const unsigned int* __restrict__ flag,
                       unsigned int* __restrict__ packed){
  const int t = threadIdx.x;
  const int row = blockIdx.x*4 + (t >> 6);
  const int w = t & 63;
  const size_t base = (size_t)row*TE + (size_t)w*32;
  unsigned int bits = 0;
  if(*flag){
    const unsigned int* p = mraw + base;
    #pragma unroll
    for(int j=0;j<32;j++) bits |= (p[j] & 1u) << j;
  } else {
    const unsigned char* p = (const unsigned char*)mraw + base;
    #pragma unroll
    for(int j=0;j<32;j++) bits |= (unsigned int)(p[j] != 0) << j;
  }
  packed[(size_t)row*64 + w] = bits;
}

// ---------------- denom[b][k] = sum_q mask[b][q][k] (from packed bits) ----------------
__global__ __launch_bounds__(256) void k_denom(const unsigned int* __restrict__ packed,
                        float* __restrict__ denom){
  const int b = blockIdx.z;
  const int k = blockIdx.x*256 + threadIdx.x;
  const int q0 = blockIdx.y*64;
  const unsigned int* p = packed + ((size_t)b*TE + q0)*64 + (k >> 5);
  const unsigned sh = k & 31;
  int cnt = 0;
  #pragma unroll 8
  for(int q=0;q<64;q++) cnt += (p[(size_t)q*64] >> sh) & 1u;
  atomicAdd(&denom[b*TE + k], (float)cnt);
}

// ---------------- transpose + LayerNorm + Q/K/V projections (fp16 out) ----------------
__global__ __launch_bounds__(256) void k_qkv(
    const float* __restrict__ x, const float* __restrict__ wqs, const float* __restrict__ wks,
    const float* __restrict__ wvs, const float* __restrict__ gamma, const float* __restrict__ beta,
    _Float16* __restrict__ qh, _Float16* __restrict__ kh, _Float16* __restrict__ vt){
  __shared__ float xs[16][260];
  __shared__ float qi[16][260];
  __shared__ float mu_s[16], rs_s[16];
  const int t = threadIdx.x;
  const int b = blockIdx.y;
  const int e0 = blockIdx.x*16;

  for(int i=t;i<16*256;i+=256){
    int el = i & 15, dd = i >> 4;
    xs[el][dd] = x[((size_t)(b*TD + dd))*TE + e0 + el];
  }
  __syncthreads();
  {
    int row = t >> 4, j = t & 15;
    float s1=0.f, s2=0.f;
    #pragma unroll
    for(int i=0;i<16;i++){ float v = xs[row][j*16+i]; s1 += v; s2 += v*v; }
    #pragma unroll
    for(int off=1; off<16; off<<=1){ s1 += __shfl_xor(s1, off); s2 += __shfl_xor(s2, off); }
    if(j==0){
      float m = s1 * (1.f/256.f);
      float var = s2 * (1.f/256.f) - m*m;
      mu_s[row] = m;
      rs_s[row] = rsqrtf(var + 1e-6f);
    }
  }
  __syncthreads();
  for(int i=t;i<16*256;i+=256){
    int r = i >> 8, dd = i & 255;
    qi[r][dd] = (xs[r][dd] - mu_s[r]) * rs_s[r] * gamma[dd] + beta[dd];
  }
  __syncthreads();

  const int c = t;
  float aq[16], ak[16], av[16];
  #pragma unroll
  for(int r=0;r<16;r++){ aq[r]=0.f; ak[r]=0.f; av[r]=0.f; }
  for(int dd=0; dd<256; dd+=4){
    float wq0 = wqs[(dd+0)*256 + c], wq1 = wqs[(dd+1)*256 + c];
    float wq2 = wqs[(dd+2)*256 + c], wq3 = wqs[(dd+3)*256 + c];
    float wk0 = wks[(dd+0)*256 + c], wk1 = wks[(dd+1)*256 + c];
    float wk2 = wks[(dd+2)*256 + c], wk3 = wks[(dd+3)*256 + c];
    float wv0 = wvs[(dd+0)*256 + c], wv1 = wvs[(dd+1)*256 + c];
    float wv2 = wvs[(dd+2)*256 + c], wv3 = wvs[(dd+3)*256 + c];
    #pragma unroll
    for(int r=0;r<16;r++){
      float4 a  = *(const float4*)&qi[r][dd];
      float4 s4 = *(const float4*)&xs[r][dd];
      aq[r] += a.x*wq0  + a.y*wq1  + a.z*wq2  + a.w*wq3;
      ak[r] += s4.x*wk0 + s4.y*wk1 + s4.z*wk2 + s4.w*wk3;
      av[r] += s4.x*wv0 + s4.y*wv1 + s4.z*wv2 + s4.w*wv3;
    }
  }
  const int hh = c >> 5, d2 = c & 31;
  const float scl = 0.17677669529663687f;   // 1/sqrt(DK)
  const size_t hb = ((size_t)(b*TH + hh))*TE;
  #pragma unroll
  for(int r=0;r<16;r++){
    size_t idx = (hb + e0 + r)*32 + d2;
    qh[idx] = (_Float16)(aq[r]*scl);
    kh[idx] = (_Float16)(ak[r]);
  }
  // V transposed: [bh][32][E]
  unsigned int pk[8];
  #pragma unroll
  for(int i2=0;i2<8;i2++) pk[i2] = packh2(av[2*i2], av[2*i2+1]);
  _Float16* vr = vt + ((size_t)(b*TH + hh)*32 + d2)*TE + e0;
  *(uint4*)&vr[0] = *(const uint4*)&pk[0];
  *(uint4*)&vr[8] = *(const uint4*)&pk[4];
}

// ---------------- MFMA attention, barrier-free K loop ----------------
// 1 block = 64 q-rows of one (b,h). 4 waves x 16 rows. Two passes over K (recompute).
// K/V fragments load direct global->VGPR (L2-resident); no staging LDS, no max-sub.
__global__ __launch_bounds__(256) void k_attn(
    const _Float16* __restrict__ qh, const _Float16* __restrict__ kh, const _Float16* __restrict__ vt,
    const unsigned int* __restrict__ packed,
    float* __restrict__ attn, _Float16* __restrict__ owh, float* __restrict__ num){
  __shared__ __align__(16) _Float16 Pl[4][16][64];   // per-wave P relayout (C-frag -> A-frag)
  __shared__ unsigned int mb[64][66];                // mask bits for the 64 q-rows
  __shared__ float num_s[TE];

  const int t = threadIdx.x;
  int bid = blockIdx.x;
  bid = (bid & 7) * 256 + (bid >> 3);                // XCD-aware swizzle (2048 % 8 == 0)
  const int qt = bid & 31;
  const int bhid = bid >> 5;                         // 0..63
  const int h = bhid & 7, b = bhid >> 3;
  const size_t bh = (size_t)bhid * TE;
  const _Float16* Qg = qh + bh*32;
  const _Float16* Kg = kh + bh*32;
  const _Float16* Vg = vt + bh*32;                   // [32][TE]
  const int q0 = qt*64;

  const int wid = t >> 6, l = t & 63, g = l >> 4, c = l & 15;
  const f4 f4z = {0.f, 0.f, 0.f, 0.f};

  for(int i=t;i<TE;i+=256) num_s[i] = 0.f;
  for(int i=t;i<64*64;i+=256){
    int r = i >> 6, w = i & 63;
    mb[r][w] = packed[((size_t)b*TE + q0 + r)*64 + w];
  }
  __syncthreads();

  // Q fragment (A-operand): lane holds row (l&15) of wave tile, k = g*8..g*8+7
  const h8 qf = *(const h8*)(Qg + (size_t)(q0 + wid*16 + c)*32 + g*8);

  float ll[4] = {0.f, 0.f, 0.f, 0.f};
  float rl[4];

  // ---- pass 1: row sums of exp(s) (no max-sub; masked -> exp(-1e9)=0) ----
  for(int kt=0; kt<32; ++kt){
    h8 kf[4];
    #pragma unroll
    for(int j=0;j<4;j++) kf[j] = *(const h8*)(Kg + (size_t)(kt*64 + j*16 + c)*32 + g*8);
    f4 s[4];
    #pragma unroll
    for(int j=0;j<4;j++) s[j] = __builtin_amdgcn_mfma_f32_16x16x32_f16(qf, kf[j], f4z, 0, 0, 0);
    #pragma unroll
    for(int r=0;r<4;r++){
      const unsigned int* mrow = mb[wid*16 + 4*g + r];
      #pragma unroll
      for(int j=0;j<4;j++){
        unsigned mw = mrow[kt*2 + (j>>1)];
        float sv = ((mw >> ((j&1)*16 + c)) & 1u) ? s[j][r] : -1e9f;
        ll[r] += __expf(sv);
      }
    }
  }
  #pragma unroll
  for(int r=0;r<4;r++){
    #pragma unroll
    for(int off=1; off<16; off<<=1) ll[r] += __shfl_xor(ll[r], off);
    rl[r] = 1.f / ll[r];
  }

  // ---- pass 2: recompute, write attn (nontemporal), per-edge num, PV ----
  f4 oacc[2] = {f4z, f4z};
  for(int kt=0; kt<32; ++kt){
    h8 kf[4];
    #pragma unroll
    for(int j=0;j<4;j++) kf[j] = *(const h8*)(Kg + (size_t)(kt*64 + j*16 + c)*32 + g*8);
    f4 s[4];
    #pragma unroll
    for(int j=0;j<4;j++) s[j] = __builtin_amdgcn_mfma_f32_16x16x32_f16(qf, kf[j], f4z, 0, 0, 0);
    float* ap = attn + (bh + q0 + wid*16 + 4*g)*TE + (size_t)kt*64 + c;
    #pragma unroll
    for(int j=0;j<4;j++){
      float cs = 0.f;
      #pragma unroll
      for(int r=0;r<4;r++){
        const int qrow = 4*g + r;
        unsigned mw = mb[wid*16 + qrow][kt*2 + (j>>1)];
        float sv = ((mw >> ((j&1)*16 + c)) & 1u) ? s[j][r] : -1e9f;
        float p = __expf(sv) * rl[r];
        __builtin_nontemporal_store(p, &ap[(size_t)r*TE + j*16]);
        cs += p;
        Pl[wid][qrow][((((c + 16*j) >> 3) ^ (qrow & 7)) << 3) | (c & 7)] = (_Float16)p;
      }
      cs += __shfl_xor(cs, 16);
      cs += __shfl_xor(cs, 32);
      if(l < 16) atomicAdd(&num_s[kt*64 + j*16 + c], cs);
    }
    #pragma unroll
    for(int kc=0;kc<2;kc++){
      h8 pf = *(const h8*)&Pl[wid][c][(((kc*4+g) ^ (c & 7))) << 3];
      #pragma unroll
      for(int du=0;du<2;du++){
        h8 vf = *(const h8*)(Vg + (size_t)(du*16 + c)*TE + kt*64 + (kc*4+g)*8);
        oacc[du] = __builtin_amdgcn_mfma_f32_16x16x32_f16(pf, vf, oacc[du], 0, 0, 0);
      }
    }
  }

  // O write: [B,E,256] fp16
  #pragma unroll
  for(int du=0;du<2;du++){
    #pragma unroll
    for(int r=0;r<4;r++){
      owh[((size_t)b*TE + q0 + wid*16 + 4*g + r)*256 + h*32 + du*16 + c] = (_Float16)oacc[du][r];
    }
  }
  __syncthreads();
  for(int i=t;i<TE;i+=256) atomicAdd(&num[(size_t)b*TE + i], num_s[i]);
}

// ---------------- output projection + residual + transpose ----------------
__global__ __launch_bounds__(256) void k_fc(
    const _Float16* __restrict__ owh, const float* __restrict__ wfc, const float* __restrict__ x,
    float* __restrict__ xout){
  __shared__ float os[16][260];
  __shared__ float xt[16][260];
  const int t = threadIdx.x;
  const int b = blockIdx.y;
  const int e0 = blockIdx.x * 16;
  for(int i=t;i<512;i+=256){
    int r = i >> 5, ch = i & 31;
    h8 v = *(const h8*)&owh[((size_t)b*TE + e0 + r)*256 + ch*8];
    #pragma unroll
    for(int j=0;j<8;j++) os[r][ch*8+j] = (float)v[j];
  }
  for(int i=t;i<4096;i+=256){
    int el = i & 15, dd = i >> 4;
    xt[el][dd] = x[((size_t)(b*TD + dd))*TE + e0 + el];
  }
  __syncthreads();
  const int c = t;
  float f[16];
  #pragma unroll
  for(int r=0;r<16;r++) f[r] = 0.f;
  for(int dd=0; dd<256; dd+=4){
    float w0 = wfc[(dd+0)*256 + c], w1 = wfc[(dd+1)*256 + c];
    float w2 = wfc[(dd+2)*256 + c], w3 = wfc[(dd+3)*256 + c];
    #pragma unroll
    for(int r=0;r<16;r++){
      float4 o4 = *(const float4*)&os[r][dd];
      f[r] += o4.x*w0 + o4.y*w1 + o4.z*w2 + o4.w*w3;
    }
  }
  __syncthreads();
  #pragma unroll
  for(int r=0;r<16;r++) os[r][c] = f[r] + xt[r][c];
  __syncthreads();
  for(int i=t;i<4096;i+=256){
    int el = i & 15, dd = i >> 4;
    xout[((size_t)(b*TD + dd))*TE + e0 + el] = os[el][dd];
  }
}

// ---------------- per-edge final: num / (H * denom) ----------------
__global__ void k_edge(const float* __restrict__ num, const float* __restrict__ denom,
                       float* __restrict__ pe){
  int idx = blockIdx.x*256 + threadIdx.x;
  pe[idx] = num[idx] / (8.f * denom[idx]);
}

extern "C" void kernel_launch(void* const* d_in, const int* in_sizes, int n_in,
                              void* d_out, int out_size, void* d_ws, size_t ws_size,
                              hipStream_t stream){
  const float* x   = (const float*)d_in[0];
  const unsigned int* mraw = (const unsigned int*)d_in[1];
  const float* wqs = (const float*)d_in[2];
  const float* wks = (const float*)d_in[3];
  const float* wvs = (const float*)d_in[4];
  const float* wfc = (const float*)d_in[5];
  const float* gamma = (const float*)d_in[6];
  const float* beta  = (const float*)d_in[7];

  float* xout = (float*)d_out;                               // [B,D,E]
  float* attn = xout + (size_t)TB*TD*TE;                     // [B,H,E,E]
  float* pe   = attn + (size_t)TB*TH*TE*TE;                  // [B,E]

  const size_t SZ = (size_t)TB*TH*TE*32;                     // 4,194,304
  unsigned int* flag = (unsigned int*)d_ws;
  _Float16* qhp = (_Float16*)((char*)d_ws + 256);
  _Float16* khp = qhp + SZ;
  _Float16* vtp = khp + SZ;                                  // V^T [B,H,32,E]
  _Float16* owh = vtp + SZ;                                  // [B,E,256] fp16
  unsigned int* packed = (unsigned int*)(owh + SZ);          // 4 MB
  float* num   = (float*)(packed + (size_t)TB*TE*64);
  float* denom = num + (size_t)TB*TE;

  hipMemsetAsync(num, 0, (size_t)TB*TE*2*sizeof(float), stream);
  k_detect<<<1, 256, 0, stream>>>(mraw, flag);
  k_pack<<<TB*TE/4, 256, 0, stream>>>(mraw, flag, packed);
  k_denom<<<dim3(TE/256, TE/64, TB), 256, 0, stream>>>(packed, denom);
  k_qkv<<<dim3(TE/16, TB), 256, 0, stream>>>(x, wqs, wks, wvs, gamma, beta, qhp, khp, vtp);
  k_attn<<<TB*TH*TE/64, 256, 0, stream>>>(qhp, khp, vtp, packed, attn, owh, num);
  k_fc<<<dim3(TE/16, TB), 256, 0, stream>>>(owh, wfc, x, xout);
  k_edge<<<TB*TE/256, 256, 0, stream>>>(num, denom, pe);
}

// Round 4
// 529.644 us; speedup vs baseline: 6.6656x; 1.0950x over previous
//
#include <hip/hip_runtime.h>
#include <hip/hip_fp16.h>

#define TB 8      // batch
#define TD 256    // d_model
#define TE 2048   // edges (sequence)
#define TH 8      // heads

typedef _Float16 h8 __attribute__((ext_vector_type(8)));
typedef _Float16 h4 __attribute__((ext_vector_type(4)));
typedef _Float16 h2_t __attribute__((ext_vector_type(2)));
typedef float    f4 __attribute__((ext_vector_type(4)));

static __device__ __forceinline__ unsigned int packh2(float a, float b){
  __half2 h = __floats2half2_rn(a, b);
  return __builtin_bit_cast(unsigned int, h);
}
static __device__ __forceinline__ h2_t u2h(unsigned int u){
  return __builtin_bit_cast(h2_t, u);
}
static __device__ __forceinline__ float fdot2f(h2_t a, h2_t b, float c){
#if __has_builtin(__builtin_amdgcn_fdot2)
  return __builtin_amdgcn_fdot2(a, b, c, false);
#else
  return c + (float)a[0]*(float)b[0] + (float)a[1]*(float)b[1];
#endif
}
static __device__ __forceinline__ unsigned int pkadd(unsigned int a, unsigned int b){
  __half2 x = __builtin_bit_cast(__half2, a);
  __half2 y = __builtin_bit_cast(__half2, b);
  return __builtin_bit_cast(unsigned int, __hadd2(x, y));
}

// ---------------- mask dtype detection: 1 = int32, 0 = bytes ----------------
__global__ void k_detect(const unsigned int* __restrict__ mraw, unsigned int* __restrict__ flag){
  __shared__ int oks;
  if(threadIdx.x == 0) oks = 1;
  __syncthreads();
  int ok = 1;
  for(int i = threadIdx.x; i < 4096; i += 256){
    if(mraw[i] > 1u) ok = 0;
  }
  if(!ok) atomicAnd(&oks, 0);
  __syncthreads();
  if(threadIdx.x == 0) *flag = (unsigned int)oks;
}

// ---------------- pack mask rows into bitmask [B*E][64 words] ----------------
__global__ __launch_bounds__(256) void k_pack(const unsigned int* __restrict__ mraw,
                       const unsigned int* __restrict__ flag,
                       unsigned int* __restrict__ packed){
  const int t = threadIdx.x;
  const int row = blockIdx.x*4 + (t >> 6);
  const int w = t & 63;
  const size_t base = (size_t)row*TE + (size_t)w*32;
  unsigned int bits = 0;
  if(*flag){
    const unsigned int* p = mraw + base;
    #pragma unroll
    for(int j=0;j<32;j++) bits |= (p[j] & 1u) << j;
  } else {
    const unsigned char* p = (const unsigned char*)mraw + base;
    #pragma unroll
    for(int j=0;j<32;j++) bits |= (unsigned int)(p[j] != 0) << j;
  }
  packed[(size_t)row*64 + w] = bits;
}

// ---------------- denom[b][k] = sum_q mask[b][q][k] (from packed bits) ----------------
__global__ __launch_bounds__(256) void k_denom(const unsigned int* __restrict__ packed,
                        float* __restrict__ denom){
  const int b = blockIdx.z;
  const int k = blockIdx.x*256 + threadIdx.x;
  const int q0 = blockIdx.y*64;
  const unsigned int* p = packed + ((size_t)b*TE + q0)*64 + (k >> 5);
  const unsigned sh = k & 31;
  int cnt = 0;
  #pragma unroll 8
  for(int q=0;q<64;q++) cnt += (p[(size_t)q*64] >> sh) & 1u;
  atomicAdd(&denom[b*TE + k], (float)cnt);
}

// ---------------- weight pre-pack: f32 [256][256] -> fp16-pair uint [128][256] ----------------
__global__ __launch_bounds__(256) void k_wpack(
    const float* __restrict__ wqs, const float* __restrict__ wks,
    const float* __restrict__ wvs, const float* __restrict__ wfc,
    unsigned int* __restrict__ wq2, unsigned int* __restrict__ wk2,
    unsigned int* __restrict__ wv2, unsigned int* __restrict__ wf2){
  const int idx = blockIdx.x*256 + threadIdx.x;      // 4*32768
  const int m = idx >> 15;
  const int r = idx & 32767;
  const int dd2 = r >> 8, cc = r & 255;
  const float* src = (m==0) ? wqs : (m==1) ? wks : (m==2) ? wvs : wfc;
  unsigned int* dst = (m==0) ? wq2 : (m==1) ? wk2 : (m==2) ? wv2 : wf2;
  dst[dd2*256 + cc] = packh2(src[(2*dd2)*256 + cc], src[(2*dd2+1)*256 + cc]);
}

// ---------------- transpose + LayerNorm + Q/K/V projections (fdot2, fp16 out) ----------------
__global__ __launch_bounds__(256) void k_qkv(
    const float* __restrict__ x,
    const unsigned int* __restrict__ wq2, const unsigned int* __restrict__ wk2,
    const unsigned int* __restrict__ wv2,
    const float* __restrict__ gamma, const float* __restrict__ beta,
    _Float16* __restrict__ qh, _Float16* __restrict__ kh, _Float16* __restrict__ vt){
  __shared__ float xs[16][260];
  __shared__ unsigned int qi2[16][132];
  __shared__ unsigned int xs2[16][132];
  __shared__ float mu_s[16], rs_s[16];
  const int t = threadIdx.x;
  const int b = blockIdx.y;
  const int e0 = blockIdx.x*16;

  for(int i=t;i<16*256;i+=256){
    int el = i & 15, dd = i >> 4;
    xs[el][dd] = x[((size_t)(b*TD + dd))*TE + e0 + el];
  }
  __syncthreads();
  {
    int row = t >> 4, j = t & 15;
    float s1=0.f, s2=0.f;
    #pragma unroll
    for(int i=0;i<16;i++){ float v = xs[row][j*16+i]; s1 += v; s2 += v*v; }
    #pragma unroll
    for(int off=1; off<16; off<<=1){ s1 += __shfl_xor(s1, off); s2 += __shfl_xor(s2, off); }
    if(j==0){
      float m = s1 * (1.f/256.f);
      float var = s2 * (1.f/256.f) - m*m;
      mu_s[row] = m;
      rs_s[row] = rsqrtf(var + 1e-6f);
    }
  }
  __syncthreads();
  for(int i=t;i<16*128;i+=256){
    int r = i >> 7, dd2 = i & 127;
    float x0 = xs[r][2*dd2], x1 = xs[r][2*dd2+1];
    xs2[r][dd2] = packh2(x0, x1);
    float q0v = (x0 - mu_s[r]) * rs_s[r] * gamma[2*dd2]   + beta[2*dd2];
    float q1v = (x1 - mu_s[r]) * rs_s[r] * gamma[2*dd2+1] + beta[2*dd2+1];
    qi2[r][dd2] = packh2(q0v, q1v);
  }
  __syncthreads();

  const int c = t;
  float aq[16], ak[16], av[16];
  #pragma unroll
  for(int r=0;r<16;r++){ aq[r]=0.f; ak[r]=0.f; av[r]=0.f; }
  for(int dd2=0; dd2<128; dd2+=4){
    unsigned int wq[4], wk[4], wv[4];
    #pragma unroll
    for(int u=0;u<4;u++){
      wq[u] = wq2[(dd2+u)*256 + c];
      wk[u] = wk2[(dd2+u)*256 + c];
      wv[u] = wv2[(dd2+u)*256 + c];
    }
    #pragma unroll
    for(int r=0;r<16;r++){
      uint4 a4 = *(const uint4*)&qi2[r][dd2];
      uint4 s4 = *(const uint4*)&xs2[r][dd2];
      aq[r] = fdot2f(u2h(a4.x), u2h(wq[0]), aq[r]);
      aq[r] = fdot2f(u2h(a4.y), u2h(wq[1]), aq[r]);
      aq[r] = fdot2f(u2h(a4.z), u2h(wq[2]), aq[r]);
      aq[r] = fdot2f(u2h(a4.w), u2h(wq[3]), aq[r]);
      ak[r] = fdot2f(u2h(s4.x), u2h(wk[0]), ak[r]);
      ak[r] = fdot2f(u2h(s4.y), u2h(wk[1]), ak[r]);
      ak[r] = fdot2f(u2h(s4.z), u2h(wk[2]), ak[r]);
      ak[r] = fdot2f(u2h(s4.w), u2h(wk[3]), ak[r]);
      av[r] = fdot2f(u2h(s4.x), u2h(wv[0]), av[r]);
      av[r] = fdot2f(u2h(s4.y), u2h(wv[1]), av[r]);
      av[r] = fdot2f(u2h(s4.z), u2h(wv[2]), av[r]);
      av[r] = fdot2f(u2h(s4.w), u2h(wv[3]), av[r]);
    }
  }
  const int hh = c >> 5, d2 = c & 31;
  const float scl = 0.17677669529663687f;   // 1/sqrt(DK)
  const size_t hb = ((size_t)(b*TH + hh))*TE;
  #pragma unroll
  for(int r=0;r<16;r++){
    size_t idx = (hb + e0 + r)*32 + d2;
    qh[idx] = (_Float16)(aq[r]*scl);
    kh[idx] = (_Float16)(ak[r]);
  }
  // V transposed: [bh][32][E]
  unsigned int pk[8];
  #pragma unroll
  for(int i2=0;i2<8;i2++) pk[i2] = packh2(av[2*i2], av[2*i2+1]);
  _Float16* vr = vt + ((size_t)(b*TH + hh)*32 + d2)*TE + e0;
  *(uint4*)&vr[0] = *(const uint4*)&pk[0];
  *(uint4*)&vr[8] = *(const uint4*)&pk[4];
}

// ---------------- MFMA attention, swapped-operand, float4 stores, no P-LDS ----------------
// 1 block = 64 q-rows of one (b,h). 4 waves x 16 rows. Two passes over K.
// QK^T as mfma(K,Q): lane c = q-row, regs (g,r) = k = j*16+4g+r (4 consecutive k per frag).
// PV contraction-dim permuted so P fragments are lane-local: k(slot) = 32kc+16h+4g+r.
__global__ __launch_bounds__(256) void k_attn(
    const _Float16* __restrict__ qh, const _Float16* __restrict__ kh, const _Float16* __restrict__ vt,
    const unsigned int* __restrict__ packed,
    float* __restrict__ attn, _Float16* __restrict__ owh, float* __restrict__ num){
  __shared__ unsigned int mb[64][66];
  __shared__ float num_s[TE];

  const int t = threadIdx.x;
  int bid = blockIdx.x;
  bid = (bid & 7) * 256 + (bid >> 3);                // XCD-aware swizzle (2048 % 8 == 0)
  const int qt = bid & 31;
  const int bhid = bid >> 5;                         // 0..63
  const int h = bhid & 7, b = bhid >> 3;
  const size_t bh = (size_t)bhid * TE;
  const _Float16* Qg = qh + bh*32;
  const _Float16* Kg = kh + bh*32;
  const _Float16* Vg = vt + bh*32;                   // [32][TE]
  const int q0 = qt*64;

  const int wid = t >> 6, l = t & 63, g = l >> 4, c = l & 15;
  const int qr = wid*16 + c;
  const f4 f4z = {0.f, 0.f, 0.f, 0.f};

  for(int i=t;i<TE;i+=256) num_s[i] = 0.f;
  for(int i=t;i<64*64;i+=256){
    int r = i >> 6, w = i & 63;
    mb[r][w] = packed[((size_t)b*TE + q0 + r)*64 + w];
  }
  __syncthreads();

  // Q fragment (B-operand): lane holds Q-row (q0+qr), k-slice g*8..g*8+7
  const h8 qf = *(const h8*)(Qg + (size_t)(q0 + qr)*32 + g*8);
  const unsigned int* mrow = mb[qr];

  // ---- pass 1: row sums of exp(s) (no max-sub; masked -> exp(-1e9)=0) ----
  float ll = 0.f;
  for(int kt=0; kt<32; ++kt){
    h8 kf[4];
    #pragma unroll
    for(int j=0;j<4;j++) kf[j] = *(const h8*)(Kg + (size_t)(kt*64 + j*16 + c)*32 + g*8);
    f4 s[4];
    #pragma unroll
    for(int j=0;j<4;j++) s[j] = __builtin_amdgcn_mfma_f32_16x16x32_f16(kf[j], qf, f4z, 0, 0, 0);
    const unsigned mw0 = mrow[kt*2], mw1 = mrow[kt*2+1];
    #pragma unroll
    for(int j=0;j<4;j++){
      const unsigned mw = (j>>1) ? mw1 : mw0;
      #pragma unroll
      for(int r=0;r<4;r++){
        float sv = ((mw >> ((j&1)*16 + 4*g + r)) & 1u) ? s[j][r] : -1e9f;
        ll += __expf(sv);
      }
    }
  }
  ll += __shfl_xor(ll, 16);
  ll += __shfl_xor(ll, 32);
  const float rl = 1.f / ll;

  // ---- pass 2: recompute, float4 NT attn stores, per-edge num, lane-local PV ----
  f4 oacc[2] = {f4z, f4z};
  float* arow = attn + (bh + q0 + qr)*TE;
  for(int kt=0; kt<32; ++kt){
    h8 kf[4];
    #pragma unroll
    for(int j=0;j<4;j++) kf[j] = *(const h8*)(Kg + (size_t)(kt*64 + j*16 + c)*32 + g*8);
    f4 s[4];
    #pragma unroll
    for(int j=0;j<4;j++) s[j] = __builtin_amdgcn_mfma_f32_16x16x32_f16(kf[j], qf, f4z, 0, 0, 0);
    const unsigned mw0 = mrow[kt*2], mw1 = mrow[kt*2+1];
    unsigned int pk[4][2];
    #pragma unroll
    for(int j=0;j<4;j++){
      const unsigned mw = (j>>1) ? mw1 : mw0;
      f4 p;
      #pragma unroll
      for(int r=0;r<4;r++){
        float sv = ((mw >> ((j&1)*16 + 4*g + r)) & 1u) ? s[j][r] : -1e9f;
        p[r] = __expf(sv) * rl;
      }
      __builtin_nontemporal_store(p, (f4*)(arow + (size_t)kt*64 + j*16 + 4*g));
      pk[j][0] = packh2(p[0], p[1]);
      pk[j][1] = packh2(p[2], p[3]);
    }
    // per-edge numerator: butterfly-sum packed fp16 over the 16 q-lanes
    unsigned int ns[8] = {pk[0][0],pk[0][1],pk[1][0],pk[1][1],pk[2][0],pk[2][1],pk[3][0],pk[3][1]};
    #pragma unroll
    for(int off=1; off<16; off<<=1){
      #pragma unroll
      for(int i2=0;i2<8;i2++) ns[i2] = pkadd(ns[i2], (unsigned)__shfl_xor((int)ns[i2], off));
    }
    if(c < 4){   // lane (c,g) flushes j=c, k = c*16+4g+r
      __half2 h0 = __builtin_bit_cast(__half2, ns[2*c]);
      __half2 h1 = __builtin_bit_cast(__half2, ns[2*c+1]);
      float* np = &num_s[kt*64 + c*16 + 4*g];
      atomicAdd(np+0, __low2float(h0));
      atomicAdd(np+1, __high2float(h0));
      atomicAdd(np+2, __low2float(h1));
      atomicAdd(np+3, __high2float(h1));
    }
    // PV: mfma(V,P) with permuted contraction dim; P fragment is lane-local
    #pragma unroll
    for(int kc=0;kc<2;kc++){
      uint4 pu = {pk[2*kc][0], pk[2*kc][1], pk[2*kc+1][0], pk[2*kc+1][1]};
      h8 pf = __builtin_bit_cast(h8, pu);
      #pragma unroll
      for(int du=0;du<2;du++){
        const _Float16* vr = Vg + (size_t)(du*16 + c)*TE + kt*64 + kc*32 + 4*g;
        h4 va = *(const h4*)(vr);
        h4 vb = *(const h4*)(vr + 16);
        h8 vf = __builtin_shufflevector(va, vb, 0,1,2,3,4,5,6,7);
        oacc[du] = __builtin_amdgcn_mfma_f32_16x16x32_f16(vf, pf, oacc[du], 0, 0, 0);
      }
    }
  }

  // O write: [B,E,256] fp16, packed 8B per (du); lane c = q-row, regs = 4 consecutive d
  #pragma unroll
  for(int du=0;du<2;du++){
    uint2 ov;
    ov.x = packh2(oacc[du][0], oacc[du][1]);
    ov.y = packh2(oacc[du][2], oacc[du][3]);
    *(uint2*)&owh[((size_t)b*TE + q0 + qr)*256 + h*32 + du*16 + 4*g] = ov;
  }
  __syncthreads();
  for(int i=t;i<TE;i+=256) atomicAdd(&num[(size_t)b*TE + i], num_s[i]);
}

// ---------------- output projection (fdot2) + residual + transpose ----------------
__global__ __launch_bounds__(256) void k_fc(
    const _Float16* __restrict__ owh, const unsigned int* __restrict__ wf2,
    const float* __restrict__ x, float* __restrict__ xout){
  __shared__ unsigned int os2[16][132];
  __shared__ float xt[16][260];
  const int t = threadIdx.x;
  const int b = blockIdx.y;
  const int e0 = blockIdx.x * 16;
  const unsigned int* ow2 = (const unsigned int*)owh;
  for(int i=t;i<16*128;i+=256){
    int r = i >> 7, dd2 = i & 127;
    os2[r][dd2] = ow2[((size_t)b*TE + e0 + r)*128 + dd2];
  }
  for(int i=t;i<4096;i+=256){
    int el = i & 15, dd = i >> 4;
    xt[el][dd] = x[((size_t)(b*TD + dd))*TE + e0 + el];
  }
  __syncthreads();
  const int c = t;
  float f[16];
  #pragma unroll
  for(int r=0;r<16;r++) f[r] = 0.f;
  for(int dd2=0; dd2<128; dd2+=4){
    unsigned int wf[4];
    #pragma unroll
    for(int u=0;u<4;u++) wf[u] = wf2[(dd2+u)*256 + c];
    #pragma unroll
    for(int r=0;r<16;r++){
      uint4 o4 = *(const uint4*)&os2[r][dd2];
      f[r] = fdot2f(u2h(o4.x), u2h(wf[0]), f[r]);
      f[r] = fdot2f(u2h(o4.y), u2h(wf[1]), f[r]);
      f[r] = fdot2f(u2h(o4.z), u2h(wf[2]), f[r]);
      f[r] = fdot2f(u2h(o4.w), u2h(wf[3]), f[r]);
    }
  }
  __syncthreads();
  #pragma unroll
  for(int r=0;r<16;r++) xt[r][c] = f[r] + xt[r][c];
  __syncthreads();
  for(int i=t;i<4096;i+=256){
    int el = i & 15, dd = i >> 4;
    xout[((size_t)(b*TD + dd))*TE + e0 + el] = xt[el][dd];
  }
}

// ---------------- per-edge final: num / (H * denom) ----------------
__global__ void k_edge(const float* __restrict__ num, const float* __restrict__ denom,
                       float* __restrict__ pe){
  int idx = blockIdx.x*256 + threadIdx.x;
  pe[idx] = num[idx] / (8.f * denom[idx]);
}

extern "C" void kernel_launch(void* const* d_in, const int* in_sizes, int n_in,
                              void* d_out, int out_size, void* d_ws, size_t ws_size,
                              hipStream_t stream){
  const float* x   = (const float*)d_in[0];
  const unsigned int* mraw = (const unsigned int*)d_in[1];
  const float* wqs = (const float*)d_in[2];
  const float* wks = (const float*)d_in[3];
  const float* wvs = (const float*)d_in[4];
  const float* wfc = (const float*)d_in[5];
  const float* gamma = (const float*)d_in[6];
  const float* beta  = (const float*)d_in[7];

  float* xout = (float*)d_out;                               // [B,D,E]
  float* attn = xout + (size_t)TB*TD*TE;                     // [B,H,E,E]
  float* pe   = attn + (size_t)TB*TH*TE*TE;                  // [B,E]

  const size_t SZ = (size_t)TB*TH*TE*32;                     // 4,194,304
  unsigned int* flag = (unsigned int*)d_ws;
  _Float16* qhp = (_Float16*)((char*)d_ws + 256);
  _Float16* khp = qhp + SZ;
  _Float16* vtp = khp + SZ;                                  // V^T [B,H,32,E]
  _Float16* owh = vtp + SZ;                                  // [B,E,256] fp16
  unsigned int* packed = (unsigned int*)(owh + SZ);          // 4 MB
  float* num   = (float*)(packed + (size_t)TB*TE*64);
  float* denom = num + (size_t)TB*TE;
  unsigned int* wq2 = (unsigned int*)(denom + (size_t)TB*TE);
  unsigned int* wk2 = wq2 + 32768;
  unsigned int* wv2 = wk2 + 32768;
  unsigned int* wf2 = wv2 + 32768;

  hipMemsetAsync(num, 0, (size_t)TB*TE*2*sizeof(float), stream);
  k_detect<<<1, 256, 0, stream>>>(mraw, flag);
  k_wpack<<<512, 256, 0, stream>>>(wqs, wks, wvs, wfc, wq2, wk2, wv2, wf2);
  k_pack<<<TB*TE/4, 256, 0, stream>>>(mraw, flag, packed);
  k_denom<<<dim3(TE/256, TE/64, TB), 256, 0, stream>>>(packed, denom);
  k_qkv<<<dim3(TE/16, TB), 256, 0, stream>>>(x, wq2, wk2, wv2, gamma, beta, qhp, khp, vtp);
  k_attn<<<TB*TH*TE/64, 256, 0, stream>>>(qhp, khp, vtp, packed, attn, owh, num);
  k_fc<<<dim3(TE/16, TB), 256, 0, stream>>>(owh, wf2, x, xout);
  k_edge<<<TB*TE/256, 256, 0, stream>>>(num, denom, pe);
}

// Round 5
// 413.453 us; speedup vs baseline: 8.5388x; 1.2810x over previous
//
#include <hip/hip_runtime.h>
#include <hip/hip_fp16.h>

#define TB 8      // batch
#define TD 256    // d_model
#define TE 2048   // edges (sequence)
#define TH 8      // heads

typedef _Float16 h8 __attribute__((ext_vector_type(8)));
typedef _Float16 h2_t __attribute__((ext_vector_type(2)));
typedef float    f4 __attribute__((ext_vector_type(4)));

static __device__ __forceinline__ unsigned int packh2(float a, float b){
  __half2 h = __floats2half2_rn(a, b);
  return __builtin_bit_cast(unsigned int, h);
}
static __device__ __forceinline__ h2_t u2h(unsigned int u){
  return __builtin_bit_cast(h2_t, u);
}
static __device__ __forceinline__ float fdot2f(h2_t a, h2_t b, float c){
#if __has_builtin(__builtin_amdgcn_fdot2)
  return __builtin_amdgcn_fdot2(a, b, c, false);
#else
  return c + (float)a[0]*(float)b[0] + (float)a[1]*(float)b[1];
#endif
}

// ---------------- pack mask rows into bitmask [B*E][64 words]; self-detecting dtype ----------------
// Every block scans the SAME first 4096 words: int32 0/1 data -> all words in {0,1};
// random bool bytes -> a >1 word within 4096 words w.p. 1-(1/8)^4096. All blocks agree.
__global__ __launch_bounds__(256) void k_pack(const unsigned int* __restrict__ mraw,
                       unsigned int* __restrict__ packed, float* __restrict__ num){
  __shared__ int oks;
  const int t = threadIdx.x;
  if(t == 0) oks = 1;
  __syncthreads();
  int ok = 1;
  for(int i=t; i<4096; i+=256) if(mraw[i] > 1u) ok = 0;
  if(!ok) atomicAnd(&oks, 0);
  __syncthreads();
  const int isInt = oks;

  const int row = blockIdx.x*4 + (t >> 6);
  const int w = t & 63;
  const size_t base = (size_t)row*TE + (size_t)w*32;
  unsigned int bits = 0;
  if(isInt){
    const unsigned int* p = mraw + base;
    #pragma unroll
    for(int j=0;j<32;j++) bits |= (p[j] & 1u) << j;
  } else {
    const unsigned char* p = (const unsigned char*)mraw + base;
    #pragma unroll
    for(int j=0;j<32;j++) bits |= (unsigned int)(p[j] != 0) << j;
  }
  packed[(size_t)row*64 + w] = bits;
  // zero the per-edge numerator buffer (16K floats) from the first 64 blocks
  if(blockIdx.x < 64) num[blockIdx.x*256 + t] = 0.f;
}

// ---------------- denom[b][k] = sum_q mask[b][q][k] (from packed bits) ----------------
__global__ __launch_bounds__(256) void k_denom(const unsigned int* __restrict__ packed,
                        float* __restrict__ denom){
  const int b = blockIdx.z;
  const int k = blockIdx.x*256 + threadIdx.x;
  const int q0 = blockIdx.y*64;
  const unsigned int* p = packed + ((size_t)b*TE + q0)*64 + (k >> 5);
  const unsigned sh = k & 31;
  int cnt = 0;
  #pragma unroll 8
  for(int q=0;q<64;q++) cnt += (p[(size_t)q*64] >> sh) & 1u;
  atomicAdd(&denom[b*TE + k], (float)cnt);
}

// ---------------- weight pre-pack: f32 [256][256] -> fp16-pair uint [128][256] ----------------
__global__ __launch_bounds__(256) void k_wpack(
    const float* __restrict__ wqs, const float* __restrict__ wks,
    const float* __restrict__ wvs, const float* __restrict__ wfc,
    unsigned int* __restrict__ wq2, unsigned int* __restrict__ wk2,
    unsigned int* __restrict__ wv2, unsigned int* __restrict__ wf2){
  const int idx = blockIdx.x*256 + threadIdx.x;      // 4*32768
  const int m = idx >> 15;
  const int r = idx & 32767;
  const int dd2 = r >> 8, cc = r & 255;
  const float* src = (m==0) ? wqs : (m==1) ? wks : (m==2) ? wvs : wfc;
  unsigned int* dst = (m==0) ? wq2 : (m==1) ? wk2 : (m==2) ? wv2 : wf2;
  dst[dd2*256 + cc] = packh2(src[(2*dd2)*256 + cc], src[(2*dd2+1)*256 + cc]);
}

// ---------------- transpose + LayerNorm + Q/K/V projections (fdot2, fp16 out) ----------------
// V output layout is k-slot-permuted: within each 32-e block, e' = 8*g + 4*jj + r
// for e = 16*jj + 4*g + r  (so attention PV B-fragments are contiguous 16B).
__global__ __launch_bounds__(256) void k_qkv(
    const float* __restrict__ x,
    const unsigned int* __restrict__ wq2, const unsigned int* __restrict__ wk2,
    const unsigned int* __restrict__ wv2,
    const float* __restrict__ gamma, const float* __restrict__ beta,
    _Float16* __restrict__ qh, _Float16* __restrict__ kh, _Float16* __restrict__ vt){
  __shared__ float xs[16][260];
  __shared__ unsigned int qi2[16][132];
  __shared__ unsigned int xs2[16][132];
  __shared__ float mu_s[16], rs_s[16];
  const int t = threadIdx.x;
  const int b = blockIdx.y;
  const int e0 = blockIdx.x*16;

  for(int i=t;i<16*256;i+=256){
    int el = i & 15, dd = i >> 4;
    xs[el][dd] = x[((size_t)(b*TD + dd))*TE + e0 + el];
  }
  __syncthreads();
  {
    int row = t >> 4, j = t & 15;
    float s1=0.f, s2=0.f;
    #pragma unroll
    for(int i=0;i<16;i++){ float v = xs[row][j*16+i]; s1 += v; s2 += v*v; }
    #pragma unroll
    for(int off=1; off<16; off<<=1){ s1 += __shfl_xor(s1, off); s2 += __shfl_xor(s2, off); }
    if(j==0){
      float m = s1 * (1.f/256.f);
      float var = s2 * (1.f/256.f) - m*m;
      mu_s[row] = m;
      rs_s[row] = rsqrtf(var + 1e-6f);
    }
  }
  __syncthreads();
  for(int i=t;i<16*128;i+=256){
    int r = i >> 7, dd2 = i & 127;
    float x0 = xs[r][2*dd2], x1 = xs[r][2*dd2+1];
    xs2[r][dd2] = packh2(x0, x1);
    float q0v = (x0 - mu_s[r]) * rs_s[r] * gamma[2*dd2]   + beta[2*dd2];
    float q1v = (x1 - mu_s[r]) * rs_s[r] * gamma[2*dd2+1] + beta[2*dd2+1];
    qi2[r][dd2] = packh2(q0v, q1v);
  }
  __syncthreads();

  const int c = t;
  float aq[16], ak[16], av[16];
  #pragma unroll
  for(int r=0;r<16;r++){ aq[r]=0.f; ak[r]=0.f; av[r]=0.f; }
  for(int dd2=0; dd2<128; dd2+=4){
    unsigned int wq[4], wk[4], wv[4];
    #pragma unroll
    for(int u=0;u<4;u++){
      wq[u] = wq2[(dd2+u)*256 + c];
      wk[u] = wk2[(dd2+u)*256 + c];
      wv[u] = wv2[(dd2+u)*256 + c];
    }
    #pragma unroll
    for(int r=0;r<16;r++){
      uint4 a4 = *(const uint4*)&qi2[r][dd2];
      uint4 s4 = *(const uint4*)&xs2[r][dd2];
      aq[r] = fdot2f(u2h(a4.x), u2h(wq[0]), aq[r]);
      aq[r] = fdot2f(u2h(a4.y), u2h(wq[1]), aq[r]);
      aq[r] = fdot2f(u2h(a4.z), u2h(wq[2]), aq[r]);
      aq[r] = fdot2f(u2h(a4.w), u2h(wq[3]), aq[r]);
      ak[r] = fdot2f(u2h(s4.x), u2h(wk[0]), ak[r]);
      ak[r] = fdot2f(u2h(s4.y), u2h(wk[1]), ak[r]);
      ak[r] = fdot2f(u2h(s4.z), u2h(wk[2]), ak[r]);
      ak[r] = fdot2f(u2h(s4.w), u2h(wk[3]), ak[r]);
      av[r] = fdot2f(u2h(s4.x), u2h(wv[0]), av[r]);
      av[r] = fdot2f(u2h(s4.y), u2h(wv[1]), av[r]);
      av[r] = fdot2f(u2h(s4.z), u2h(wv[2]), av[r]);
      av[r] = fdot2f(u2h(s4.w), u2h(wv[3]), av[r]);
    }
  }
  const int hh = c >> 5, d2 = c & 31;
  const float scl = 0.17677669529663687f;   // 1/sqrt(DK)
  const size_t hb = ((size_t)(b*TH + hh))*TE;
  #pragma unroll
  for(int r=0;r<16;r++){
    size_t idx = (hb + e0 + r)*32 + d2;
    qh[idx] = (_Float16)(aq[r]*scl);
    kh[idx] = (_Float16)(ak[r]);
  }
  // V transposed + slot-permuted: row d2, e' = (e0&~31) + 8*g + 4*jj + r
  unsigned int pk[8];
  #pragma unroll
  for(int i2=0;i2<8;i2++) pk[i2] = packh2(av[2*i2], av[2*i2+1]);
  const int jj = (e0 >> 4) & 1;
  _Float16* vr = vt + ((size_t)(b*TH + hh)*32 + d2)*TE + (e0 & ~31) + 4*jj;
  #pragma unroll
  for(int gp=0; gp<4; gp++){
    uint2 w2v; w2v.x = pk[2*gp]; w2v.y = pk[2*gp+1];
    *(uint2*)&vr[8*gp] = w2v;
  }
}

// ---------------- MFMA attention, swapped-operand, LDS-transposed full-line stores ----------------
// 1 block = 64 q-rows of one (b,h). 4 waves x 16 rows. Two passes over K.
// QK^T as mfma(K,Q): lane c = q-row, regs (j,r) with lane-group g: k = j*16+4g+r.
// Pass 2 round-trips P through a per-wave LDS strip so each NT store instruction
// covers 4 rows x 256B contiguous (full-line segments).
__global__ __launch_bounds__(256) void k_attn(
    const _Float16* __restrict__ qh, const _Float16* __restrict__ kh, const _Float16* __restrict__ vt,
    const unsigned int* __restrict__ packed,
    float* __restrict__ attn, _Float16* __restrict__ owh, float* __restrict__ num){
  __shared__ unsigned int mb[64][66];
  __shared__ float num_s[TE];
  __shared__ __align__(16) f4 S4[4][272];            // per-wave strip: 16 rows x 17 f4 (pad)

  const int t = threadIdx.x;
  int bid = blockIdx.x;
  bid = (bid & 7) * 256 + (bid >> 3);                // XCD-aware swizzle (2048 % 8 == 0)
  const int qt = bid & 31;
  const int bhid = bid >> 5;                         // 0..63
  const int h = bhid & 7, b = bhid >> 3;
  const size_t bh = (size_t)bhid * TE;
  const _Float16* Qg = qh + bh*32;
  const _Float16* Kg = kh + bh*32;
  const _Float16* Vg = vt + bh*32;                   // [32][TE], slot-permuted
  const int q0 = qt*64;

  const int wid = t >> 6, l = t & 63, g = l >> 4, c = l & 15;
  const int qr = wid*16 + c;
  const f4 f4z = {0.f, 0.f, 0.f, 0.f};

  for(int i=t;i<TE;i+=256) num_s[i] = 0.f;
  for(int i=t;i<64*64;i+=256){
    int r = i >> 6, w = i & 63;
    mb[r][w] = packed[((size_t)b*TE + q0 + r)*64 + w];
  }
  __syncthreads();

  // Q fragment (B-operand): lane holds Q-row (q0+qr), k-slice g*8..g*8+7
  const h8 qf = *(const h8*)(Qg + (size_t)(q0 + qr)*32 + g*8);
  const unsigned int* mrow = mb[qr];

  // ---- pass 1: row sums of exp(s) (no max-sub; masked -> exp(-1e9)=0) ----
  float ll = 0.f;
  for(int kt=0; kt<32; ++kt){
    h8 kf[4];
    #pragma unroll
    for(int j=0;j<4;j++) kf[j] = *(const h8*)(Kg + (size_t)(kt*64 + j*16 + c)*32 + g*8);
    f4 s[4];
    #pragma unroll
    for(int j=0;j<4;j++) s[j] = __builtin_amdgcn_mfma_f32_16x16x32_f16(kf[j], qf, f4z, 0, 0, 0);
    const unsigned mw0 = mrow[kt*2], mw1 = mrow[kt*2+1];
    #pragma unroll
    for(int j=0;j<4;j++){
      const unsigned mw = (j>>1) ? mw1 : mw0;
      #pragma unroll
      for(int r=0;r<4;r++){
        float sv = ((mw >> ((j&1)*16 + 4*g + r)) & 1u) ? s[j][r] : -1e9f;
        ll += __expf(sv);
      }
    }
  }
  ll += __shfl_xor(ll, 16);
  ll += __shfl_xor(ll, 32);
  const float rl = 1.f / ll;

  // ---- pass 2: recompute, LDS-transpose, full-line NT attn stores, num, lane-local PV ----
  f4 oacc[2] = {f4z, f4z};
  f4* Sw = S4[wid];
  float* abase = attn + (bh + q0 + wid*16)*TE;
  for(int kt=0; kt<32; ++kt){
    h8 kf[4];
    #pragma unroll
    for(int j=0;j<4;j++) kf[j] = *(const h8*)(Kg + (size_t)(kt*64 + j*16 + c)*32 + g*8);
    f4 s[4];
    #pragma unroll
    for(int j=0;j<4;j++) s[j] = __builtin_amdgcn_mfma_f32_16x16x32_f16(kf[j], qf, f4z, 0, 0, 0);
    const unsigned mw0 = mrow[kt*2], mw1 = mrow[kt*2+1];
    unsigned int pk[4][2];
    #pragma unroll
    for(int j=0;j<4;j++){
      const unsigned mw = (j>>1) ? mw1 : mw0;
      f4 p;
      #pragma unroll
      for(int r=0;r<4;r++){
        float sv = ((mw >> ((j&1)*16 + 4*g + r)) & 1u) ? s[j][r] : -1e9f;
        p[r] = __expf(sv) * rl;
      }
      Sw[c*17 + 4*j + g] = p;                       // strip write (2-way banks, free)
      pk[j][0] = packh2(p[0], p[1]);
      pk[j][1] = packh2(p[2], p[3]);
    }
    // PV first (overlaps strip-write latency): mfma(V,P), V-frag one contiguous h8
    #pragma unroll
    for(int kc=0;kc<2;kc++){
      uint4 pu = {pk[2*kc][0], pk[2*kc][1], pk[2*kc+1][0], pk[2*kc+1][1]};
      h8 pf = __builtin_bit_cast(h8, pu);
      #pragma unroll
      for(int du=0;du<2;du++){
        h8 vf = *(const h8*)(Vg + (size_t)(du*16 + c)*TE + kt*64 + kc*32 + g*8);
        oacc[du] = __builtin_amdgcn_mfma_f32_16x16x32_f16(vf, pf, oacc[du], 0, 0, 0);
      }
    }
    // read back transposed: lane l -> rows {u*4+g}, chunk c (4 rows x 256B per store instr)
    f4 v[4];
    #pragma unroll
    for(int u=0;u<4;u++) v[u] = Sw[(u*4+g)*17 + c];
    #pragma unroll
    for(int u=0;u<4;u++)
      __builtin_nontemporal_store(v[u], (f4*)(abase + (size_t)(u*4+g)*TE + kt*64 + c*4));
    f4 a = v[0] + v[1] + v[2] + v[3];
    #pragma unroll
    for(int q=0;q<4;q++){ a[q] += __shfl_xor(a[q], 16); a[q] += __shfl_xor(a[q], 32); }
    if(l < 16){
      float* np = &num_s[kt*64 + c*4];
      atomicAdd(np+0, a[0]); atomicAdd(np+1, a[1]);
      atomicAdd(np+2, a[2]); atomicAdd(np+3, a[3]);
    }
  }

  // O write: [B,E,256] fp16; lane c = q-row, regs = 4 consecutive d
  #pragma unroll
  for(int du=0;du<2;du++){
    uint2 ov;
    ov.x = packh2(oacc[du][0], oacc[du][1]);
    ov.y = packh2(oacc[du][2], oacc[du][3]);
    *(uint2*)&owh[((size_t)b*TE + q0 + qr)*256 + h*32 + du*16 + 4*g] = ov;
  }
  __syncthreads();
  for(int i=t;i<TE;i+=256) atomicAdd(&num[(size_t)b*TE + i], num_s[i]);
}

// ---------------- output projection (fdot2) + residual + transpose ----------------
__global__ __launch_bounds__(256) void k_fc(
    const _Float16* __restrict__ owh, const unsigned int* __restrict__ wf2,
    const float* __restrict__ x, float* __restrict__ xout){
  __shared__ unsigned int os2[16][132];
  __shared__ float xt[16][260];
  const int t = threadIdx.x;
  const int b = blockIdx.y;
  const int e0 = blockIdx.x * 16;
  const unsigned int* ow2 = (const unsigned int*)owh;
  for(int i=t;i<16*128;i+=256){
    int r = i >> 7, dd2 = i & 127;
    os2[r][dd2] = ow2[((size_t)b*TE + e0 + r)*128 + dd2];
  }
  for(int i=t;i<4096;i+=256){
    int el = i & 15, dd = i >> 4;
    xt[el][dd] = x[((size_t)(b*TD + dd))*TE + e0 + el];
  }
  __syncthreads();
  const int c = t;
  float f[16];
  #pragma unroll
  for(int r=0;r<16;r++) f[r] = 0.f;
  for(int dd2=0; dd2<128; dd2+=4){
    unsigned int wf[4];
    #pragma unroll
    for(int u=0;u<4;u++) wf[u] = wf2[(dd2+u)*256 + c];
    #pragma unroll
    for(int r=0;r<16;r++){
      uint4 o4 = *(const uint4*)&os2[r][dd2];
      f[r] = fdot2f(u2h(o4.x), u2h(wf[0]), f[r]);
      f[r] = fdot2f(u2h(o4.y), u2h(wf[1]), f[r]);
      f[r] = fdot2f(u2h(o4.z), u2h(wf[2]), f[r]);
      f[r] = fdot2f(u2h(o4.w), u2h(wf[3]), f[r]);
    }
  }
  __syncthreads();
  #pragma unroll
  for(int r=0;r<16;r++) xt[r][c] = f[r] + xt[r][c];
  __syncthreads();
  for(int i=t;i<4096;i+=256){
    int el = i & 15, dd = i >> 4;
    xout[((size_t)(b*TD + dd))*TE + e0 + el] = xt[el][dd];
  }
}

// ---------------- per-edge final: num / (H * denom) ----------------
__global__ void k_edge(const float* __restrict__ num, const float* __restrict__ denom,
                       float* __restrict__ pe){
  int idx = blockIdx.x*256 + threadIdx.x;
  pe[idx] = num[idx] / (8.f * denom[idx]);
}

extern "C" void kernel_launch(void* const* d_in, const int* in_sizes, int n_in,
                              void* d_out, int out_size, void* d_ws, size_t ws_size,
                              hipStream_t stream){
  const float* x   = (const float*)d_in[0];
  const unsigned int* mraw = (const unsigned int*)d_in[1];
  const float* wqs = (const float*)d_in[2];
  const float* wks = (const float*)d_in[3];
  const float* wvs = (const float*)d_in[4];
  const float* wfc = (const float*)d_in[5];
  const float* gamma = (const float*)d_in[6];
  const float* beta  = (const float*)d_in[7];

  float* xout = (float*)d_out;                               // [B,D,E]
  float* attn = xout + (size_t)TB*TD*TE;                     // [B,H,E,E]
  float* pe   = attn + (size_t)TB*TH*TE*TE;                  // [B,E]

  const size_t SZ = (size_t)TB*TH*TE*32;                     // 4,194,304
  _Float16* qhp = (_Float16*)((char*)d_ws + 256);
  _Float16* khp = qhp + SZ;
  _Float16* vtp = khp + SZ;                                  // V^T [B,H,32,E] slot-permuted
  _Float16* owh = vtp + SZ;                                  // [B,E,256] fp16
  unsigned int* packed = (unsigned int*)(owh + SZ);          // 4 MB
  float* num   = (float*)(packed + (size_t)TB*TE*64);
  float* denom = num + (size_t)TB*TE;
  unsigned int* wq2 = (unsigned int*)(denom + (size_t)TB*TE);
  unsigned int* wk2 = wq2 + 32768;
  unsigned int* wv2 = wk2 + 32768;
  unsigned int* wf2 = wv2 + 32768;

  hipMemsetAsync(denom, 0, (size_t)TB*TE*sizeof(float), stream);
  k_wpack<<<512, 256, 0, stream>>>(wqs, wks, wvs, wfc, wq2, wk2, wv2, wf2);
  k_pack<<<TB*TE/4, 256, 0, stream>>>(mraw, packed, num);
  k_denom<<<dim3(TE/256, TE/64, TB), 256, 0, stream>>>(packed, denom);
  k_qkv<<<dim3(TE/16, TB), 256, 0, stream>>>(x, wq2, wk2, wv2, gamma, beta, qhp, khp, vtp);
  k_attn<<<TB*TH*TE/64, 256, 0, stream>>>(qhp, khp, vtp, packed, attn, owh, num);
  k_fc<<<dim3(TE/16, TB), 256, 0, stream>>>(owh, wf2, x, xout);
  k_edge<<<TB*TE/256, 256, 0, stream>>>(num, denom, pe);
}